// Round 7
// baseline (158.065 us; speedup 1.0000x reference)
//
#include <hip/hip_runtime.h>
#include <math.h>

// TripletHard B=8192 D=128 NC=256. Round-7 design:
//   prep : fp32->bf16 (RNE), K-major fbT, sq of rounded values.
//   work : 1D grid 768 = 256 pos-blocks (per-class Gram -> 2nd-smallest
//          same-class d2) + 512 main-blocks (neg-only diff-class min,
//          software-pipelined s-loop, 3 waves/SIMD). Pos is independent of
//          main, so fusing removes r6's serialization + memset launches.
//   merge: combine 16 n1 slices + pos_d2 -> mean hinge (device atomics).
// fbT8[kc*8192 + row] = features[row][kc*8..kc*8+7], kc=0..15.

#define BN 8192
#define MARGIN_F 1.0f
#define EPS_F 1e-5f

typedef __attribute__((ext_vector_type(8))) short short8;
typedef __attribute__((ext_vector_type(4))) float floatx4;

__device__ __forceinline__ unsigned short bf16_rne(float x, float& r) {
    unsigned u = __float_as_uint(x);
    u += 0x7FFF + ((u >> 16) & 1);
    unsigned short h = (unsigned short)(u >> 16);
    r = __uint_as_float(((unsigned)h) << 16);
    return h;
}

// 4 threads/row: bf16 convert, K-major write, sq from ROUNDED values.
__global__ __launch_bounds__(256) void prep_kernel(const float* __restrict__ f,
                                                   short8* __restrict__ fbT,
                                                   float* __restrict__ sq,
                                                   float* __restrict__ g_acc,
                                                   unsigned* __restrict__ counter) {
    int gid = blockIdx.x * 256 + threadIdx.x;  // 0..32767
    if (gid == 0) { *g_acc = 0.f; *counter = 0u; }
    int row = gid >> 2, part = gid & 3;
    const float4* f4 = (const float4*)f + (size_t)row * 32 + part * 8;
    float s = 0.f;
#pragma unroll
    for (int cc = 0; cc < 4; ++cc) {  // chunk kc = part*4 + cc
        float4 v0 = f4[cc * 2], v1 = f4[cc * 2 + 1];
        float r0, r1, r2, r3, r4, r5, r6, r7;
        short8 o;
        o[0] = (short)bf16_rne(v0.x, r0);
        o[1] = (short)bf16_rne(v0.y, r1);
        o[2] = (short)bf16_rne(v0.z, r2);
        o[3] = (short)bf16_rne(v0.w, r3);
        o[4] = (short)bf16_rne(v1.x, r4);
        o[5] = (short)bf16_rne(v1.y, r5);
        o[6] = (short)bf16_rne(v1.z, r6);
        o[7] = (short)bf16_rne(v1.w, r7);
        fbT[(size_t)(part * 4 + cc) * BN + row] = o;
        s += r0 * r0 + r1 * r1 + r2 * r2 + r3 * r3 +
             r4 * r4 + r5 * r5 + r6 * r6 + r7 * r7;
    }
    s += __shfl_xor(s, 1, 4);
    s += __shfl_xor(s, 2, 4);
    if (part == 0) sq[row] = s;
}

// Fused work kernel. Blocks [0,256): pos (class = bid). Blocks [256,768):
// main, mbid = bid-256: i-block = mbid&31 (4 waves x 64-row strips),
// j-split g = mbid>>5 covers cols [g*512, g*512+512) as 32 16-col steps.
__global__ __launch_bounds__(256, 3) void work_kernel(const short8* __restrict__ fbT,
                                                      const int* __restrict__ lbl,
                                                      const float* __restrict__ sq,
                                                      float* __restrict__ part,
                                                      float* __restrict__ pos_d2) {
    const int t = threadIdx.x;
    const int lane = t & 63;
    const int wv = t >> 6;
    const int q = lane >> 4, c = lane & 15;
    const int bid = blockIdx.x;

    if (bid < 256) {
        // ---------------- pos path: per-class 2nd-smallest same-class d2 ---
        __shared__ int midx[256];
        __shared__ int cnt;
        const int cls = bid;
        if (t == 0) cnt = 0;
        __syncthreads();
        for (int r = t; r < BN; r += 256) {
            if (lbl[r] == cls) {
                int p = atomicAdd(&cnt, 1);
                if (p < 256) midx[p] = r;
            }
        }
        __syncthreads();
        int n = cnt < 256 ? cnt : 256;
        if (n == 0) return;
        int m0 = midx[0];
        if (t >= n) midx[t] = m0;  // pad all 256 slots
        __syncthreads();
        if (wv != 0) return;  // wave 0 does the Gram

        const int nt = (n + 63) >> 6;
        for (int ip = 0; ip < 2 * nt; ++ip) {  // 32 i-slots per pass (mf=2)
            short8 a[2][4];
#pragma unroll
            for (int mf = 0; mf < 2; ++mf) {
                int row = midx[ip * 32 + mf * 16 + c];
#pragma unroll
                for (int ks = 0; ks < 4; ++ks)
                    a[mf][ks] = fbT[(size_t)(ks * 4 + q) * BN + row];
            }
            float s1[2][4], s2[2][4];
#pragma unroll
            for (int mf = 0; mf < 2; ++mf)
#pragma unroll
                for (int rg = 0; rg < 4; ++rg) { s1[mf][rg] = INFINITY; s2[mf][rg] = INFINITY; }

            for (int s = 0; s < 4 * nt; ++s) {  // 16 j-slots per step
                int jslot = s * 16 + c;
                int jrow = midx[jslot];
                short8 b[4];
#pragma unroll
                for (int ks = 0; ks < 4; ++ks)
                    b[ks] = fbT[(size_t)(ks * 4 + q) * BN + jrow];
                float sj = sq[jrow];
                bool valid = (jslot < n);

                floatx4 acc[2];
#pragma unroll
                for (int mf = 0; mf < 2; ++mf) acc[mf] = (floatx4)0.f;
#pragma unroll
                for (int ks = 0; ks < 4; ++ks)
#pragma unroll
                    for (int mf = 0; mf < 2; ++mf)
                        acc[mf] = __builtin_amdgcn_mfma_f32_16x16x32_bf16(
                            a[mf][ks], b[ks], acc[mf], 0, 0, 0);
#pragma unroll
                for (int mf = 0; mf < 2; ++mf)
#pragma unroll
                    for (int rg = 0; rg < 4; ++rg) {
                        float v = fmaf(-2.0f, acc[mf][rg], sj);
                        float vs = valid ? v : INFINITY;
                        s2[mf][rg] = fminf(s2[mf][rg], fmaxf(s1[mf][rg], vs));
                        s1[mf][rg] = fminf(s1[mf][rg], vs);
                    }
            }
#pragma unroll
            for (int m = 1; m < 16; m <<= 1) {
#pragma unroll
                for (int mf = 0; mf < 2; ++mf)
#pragma unroll
                    for (int rg = 0; rg < 4; ++rg) {
                        float o1 = __shfl_xor(s1[mf][rg], m, 16);
                        float o2 = __shfl_xor(s2[mf][rg], m, 16);
                        float lo = fminf(s1[mf][rg], o1);
                        float hi = fminf(fmaxf(s1[mf][rg], o1), fminf(s2[mf][rg], o2));
                        s1[mf][rg] = lo; s2[mf][rg] = hi;
                    }
            }
            if (c == 0) {
#pragma unroll
                for (int mf = 0; mf < 2; ++mf)
#pragma unroll
                    for (int rg = 0; rg < 4; ++rg) {
                        int islot = ip * 32 + mf * 16 + q * 4 + rg;
                        if (islot < n) {
                            int row = midx[islot];
                            pos_d2[row] = sq[row] + s2[mf][rg];
                        }
                    }
            }
        }
        return;
    }

    // ---------------- main path: diff-class min over a 64x512 stripe ------
    const int mbid = bid - 256;
    const int i0 = (mbid & 31) * 256 + wv * 64;
    const int g = mbid >> 5;  // 0..15
    const int jb = g * 512;

    short8 a[4][4];
#pragma unroll
    for (int mf = 0; mf < 4; ++mf) {
        int row = i0 + mf * 16 + c;
#pragma unroll
        for (int ks = 0; ks < 4; ++ks)
            a[mf][ks] = fbT[(size_t)(ks * 4 + q) * BN + row];
    }
    int li[4][4];
#pragma unroll
    for (int mf = 0; mf < 4; ++mf)
#pragma unroll
        for (int rg = 0; rg < 4; ++rg)
            li[mf][rg] = lbl[i0 + mf * 16 + q * 4 + rg];

    float n1[4][4];
#pragma unroll
    for (int mf = 0; mf < 4; ++mf)
#pragma unroll
        for (int rg = 0; rg < 4; ++rg) n1[mf][rg] = INFINITY;

    // software-pipelined 32-step scan of 16-col strips
    int jc = jb + c;
    short8 bc0 = fbT[(size_t)(q)*BN + jc];
    short8 bc1 = fbT[(size_t)(4 + q) * BN + jc];
    short8 bc2 = fbT[(size_t)(8 + q) * BN + jc];
    short8 bc3 = fbT[(size_t)(12 + q) * BN + jc];
    int ljc = lbl[jc];
    float sjc = sq[jc];

#pragma unroll
    for (int s = 0; s < 32; ++s) {
        short8 bn0, bn1, bn2, bn3;
        int ljn; float sjn;
        if (s < 31) {
            int jn = jb + (s + 1) * 16 + c;
            bn0 = fbT[(size_t)(q)*BN + jn];
            bn1 = fbT[(size_t)(4 + q) * BN + jn];
            bn2 = fbT[(size_t)(8 + q) * BN + jn];
            bn3 = fbT[(size_t)(12 + q) * BN + jn];
            ljn = lbl[jn];
            sjn = sq[jn];
        }
        floatx4 acc[4];
#pragma unroll
        for (int mf = 0; mf < 4; ++mf) acc[mf] = (floatx4)0.f;
#pragma unroll
        for (int mf = 0; mf < 4; ++mf)
            acc[mf] = __builtin_amdgcn_mfma_f32_16x16x32_bf16(a[mf][0], bc0, acc[mf], 0, 0, 0);
#pragma unroll
        for (int mf = 0; mf < 4; ++mf)
            acc[mf] = __builtin_amdgcn_mfma_f32_16x16x32_bf16(a[mf][1], bc1, acc[mf], 0, 0, 0);
#pragma unroll
        for (int mf = 0; mf < 4; ++mf)
            acc[mf] = __builtin_amdgcn_mfma_f32_16x16x32_bf16(a[mf][2], bc2, acc[mf], 0, 0, 0);
#pragma unroll
        for (int mf = 0; mf < 4; ++mf)
            acc[mf] = __builtin_amdgcn_mfma_f32_16x16x32_bf16(a[mf][3], bc3, acc[mf], 0, 0, 0);

#pragma unroll
        for (int mf = 0; mf < 4; ++mf)
#pragma unroll
            for (int rg = 0; rg < 4; ++rg) {
                float v = fmaf(-2.0f, acc[mf][rg], sjc);
                float vd = (li[mf][rg] == ljc) ? INFINITY : v;
                n1[mf][rg] = fminf(n1[mf][rg], vd);
            }
        bc0 = bn0; bc1 = bn1; bc2 = bn2; bc3 = bn3;
        ljc = ljn; sjc = sjn;
    }

    // min across the 16 c-lanes sharing each accumulator row
#pragma unroll
    for (int m = 1; m < 16; m <<= 1) {
#pragma unroll
        for (int mf = 0; mf < 4; ++mf)
#pragma unroll
            for (int rg = 0; rg < 4; ++rg)
                n1[mf][rg] = fminf(n1[mf][rg], __shfl_xor(n1[mf][rg], m, 16));
    }
    if (c == 0) {
#pragma unroll
        for (int mf = 0; mf < 4; ++mf)
#pragma unroll
            for (int rg = 0; rg < 4; ++rg)
                part[g * BN + i0 + mf * 16 + q * 4 + rg] = n1[mf][rg];
    }
}

// combine 16 n1 slices + pos_d2 -> hinge; atomic sum; last block writes mean
__global__ __launch_bounds__(128) void merge_kernel(const float* __restrict__ part,
                                                    const float* __restrict__ sq,
                                                    const float* __restrict__ pos_d2,
                                                    float* __restrict__ g_acc,
                                                    unsigned* __restrict__ counter,
                                                    float* __restrict__ out) {
    int r = blockIdx.x * 128 + threadIdx.x;
    float n = INFINITY;
#pragma unroll
    for (int k = 0; k < 16; ++k) n = fminf(n, part[k * BN + r]);
    float si = sq[r];
    float pos = sqrtf(fmaxf(pos_d2[r] + EPS_F, 0.f));
    float neg = sqrtf(fmaxf(si + n + EPS_F, 0.f));
    float h = fmaxf(MARGIN_F + pos - neg, 0.f);
    __shared__ float red[2];
#pragma unroll
    for (int m = 32; m >= 1; m >>= 1) h += __shfl_down(h, m, 64);
    if ((threadIdx.x & 63) == 0) red[threadIdx.x >> 6] = h;
    __syncthreads();
    if (threadIdx.x == 0) {
        atomicAdd(g_acc, red[0] + red[1]);
        __threadfence();
        unsigned old = atomicAdd(counter, 1u);
        if (old == 63u) {
            float tot = atomicAdd(g_acc, 0.0f);
            out[0] = tot / (float)BN;
        }
    }
}

extern "C" void kernel_launch(void* const* d_in, const int* in_sizes, int n_in,
                              void* d_out, int out_size, void* d_ws, size_t ws_size,
                              hipStream_t stream) {
    const float* f = (const float*)d_in[0];
    const int* lbl = (const int*)d_in[1];
    char* ws = (char*)d_ws;
    float* sq = (float*)ws;                                    // 32 KB
    short8* fbT = (short8*)(ws + 32768);                       // 2 MB
    float* part = (float*)(ws + 32768 + 2097152);              // 512 KB (16 slices)
    float* pos_d2 = (float*)(ws + 32768 + 2097152 + 524288);   // 32 KB
    float* g_acc = (float*)(ws + 32768 + 2097152 + 524288 + 32768);
    unsigned* counter = (unsigned*)(g_acc + 1);
    float* out = (float*)d_out;

    prep_kernel<<<128, 256, 0, stream>>>(f, fbT, sq, g_acc, counter);
    work_kernel<<<768, 256, 0, stream>>>(fbT, lbl, sq, part, pos_d2);
    merge_kernel<<<64, 128, 0, stream>>>(part, sq, pos_d2, g_acc, counter, out);
}

// Round 8
// 119.740 us; speedup vs baseline: 1.3201x; 1.3201x over previous
//
#include <hip/hip_runtime.h>
#include <math.h>

// TripletHard B=8192 D=128 NC=256. Round-8: r5 skeleton + neg-only epilogue
// + pos fused as extra blocks (no extra launch).
//   prep : fp32->bf16 (RNE), K-major fbT, sq of rounded values.
//   work : 768 blocks. [0,256): per-class Gram -> 2nd-smallest same-class d2
//          (pos_d2). [256,768): neg-only diff-class min, wave tile 64x64,
//          A-frags resident, b[4][4] batch loads from L2, barrier-free,
//          lb(256,2) so ~240 live regs fit WITHOUT spilling (r7 failure mode).
//   merge: combine 16 n1 slices + pos_d2 -> mean hinge (device atomics).
// fbT8[kc*8192 + row] = features[row][kc*8..kc*8+7], kc=0..15.

#define BN 8192
#define MARGIN_F 1.0f
#define EPS_F 1e-5f

typedef __attribute__((ext_vector_type(8))) short short8;
typedef __attribute__((ext_vector_type(4))) float floatx4;

__device__ __forceinline__ unsigned short bf16_rne(float x, float& r) {
    unsigned u = __float_as_uint(x);
    u += 0x7FFF + ((u >> 16) & 1);
    unsigned short h = (unsigned short)(u >> 16);
    r = __uint_as_float(((unsigned)h) << 16);
    return h;
}

// 4 threads/row: bf16 convert, K-major write, sq from ROUNDED values.
__global__ __launch_bounds__(256) void prep_kernel(const float* __restrict__ f,
                                                   short8* __restrict__ fbT,
                                                   float* __restrict__ sq,
                                                   float* __restrict__ g_acc,
                                                   unsigned* __restrict__ counter) {
    int gid = blockIdx.x * 256 + threadIdx.x;  // 0..32767
    if (gid == 0) { *g_acc = 0.f; *counter = 0u; }
    int row = gid >> 2, part = gid & 3;
    const float4* f4 = (const float4*)f + (size_t)row * 32 + part * 8;
    float s = 0.f;
#pragma unroll
    for (int cc = 0; cc < 4; ++cc) {  // chunk kc = part*4 + cc
        float4 v0 = f4[cc * 2], v1 = f4[cc * 2 + 1];
        float r0, r1, r2, r3, r4, r5, r6, r7;
        short8 o;
        o[0] = (short)bf16_rne(v0.x, r0);
        o[1] = (short)bf16_rne(v0.y, r1);
        o[2] = (short)bf16_rne(v0.z, r2);
        o[3] = (short)bf16_rne(v0.w, r3);
        o[4] = (short)bf16_rne(v1.x, r4);
        o[5] = (short)bf16_rne(v1.y, r5);
        o[6] = (short)bf16_rne(v1.z, r6);
        o[7] = (short)bf16_rne(v1.w, r7);
        fbT[(size_t)(part * 4 + cc) * BN + row] = o;
        s += r0 * r0 + r1 * r1 + r2 * r2 + r3 * r3 +
             r4 * r4 + r5 * r5 + r6 * r6 + r7 * r7;
    }
    s += __shfl_xor(s, 1, 4);
    s += __shfl_xor(s, 2, 4);
    if (part == 0) sq[row] = s;
}

// Fused work kernel. Blocks [0,256): pos (class = bid), wave 0 only after
// bucketing. Blocks [256,768): main, mbid = bid-256: i-block = mbid&31
// (4 waves x 64-row strips), j-split g = mbid>>5 scans 8 tiles of 64 cols.
__global__ __launch_bounds__(256, 2) void work_kernel(const short8* __restrict__ fbT,
                                                      const int* __restrict__ lbl,
                                                      const float* __restrict__ sq,
                                                      float* __restrict__ part,
                                                      float* __restrict__ pos_d2) {
    const int t = threadIdx.x;
    const int lane = t & 63;
    const int wv = t >> 6;
    const int q = lane >> 4, c = lane & 15;
    const int bid = blockIdx.x;

    if (bid < 256) {
        // ---------------- pos path: per-class 2nd-smallest same-class d2 ---
        __shared__ int midx[256];
        __shared__ int cnt;
        const int cls = bid;
        if (t == 0) cnt = 0;
        __syncthreads();
        for (int r = t; r < BN; r += 256) {
            if (lbl[r] == cls) {
                int p = atomicAdd(&cnt, 1);
                if (p < 256) midx[p] = r;
            }
        }
        __syncthreads();
        int n = cnt < 256 ? cnt : 256;
        if (n == 0) return;
        int m0 = midx[0];
        if (t >= n) midx[t] = m0;  // pad all 256 slots
        __syncthreads();
        if (wv != 0) return;  // wave 0 does the Gram

        const int nt = (n + 63) >> 6;
        for (int ip = 0; ip < 2 * nt; ++ip) {  // 32 i-slots per pass (mf=2)
            short8 a[2][4];
#pragma unroll
            for (int mf = 0; mf < 2; ++mf) {
                int row = midx[ip * 32 + mf * 16 + c];
#pragma unroll
                for (int ks = 0; ks < 4; ++ks)
                    a[mf][ks] = fbT[(size_t)(ks * 4 + q) * BN + row];
            }
            float s1[2][4], s2[2][4];
#pragma unroll
            for (int mf = 0; mf < 2; ++mf)
#pragma unroll
                for (int rg = 0; rg < 4; ++rg) { s1[mf][rg] = INFINITY; s2[mf][rg] = INFINITY; }

            for (int s = 0; s < 4 * nt; ++s) {  // 16 j-slots per step
                int jslot = s * 16 + c;
                int jrow = midx[jslot];
                short8 b[4];
#pragma unroll
                for (int ks = 0; ks < 4; ++ks)
                    b[ks] = fbT[(size_t)(ks * 4 + q) * BN + jrow];
                float sj = sq[jrow];
                bool valid = (jslot < n);

                floatx4 acc[2];
#pragma unroll
                for (int mf = 0; mf < 2; ++mf) acc[mf] = (floatx4)0.f;
#pragma unroll
                for (int ks = 0; ks < 4; ++ks)
#pragma unroll
                    for (int mf = 0; mf < 2; ++mf)
                        acc[mf] = __builtin_amdgcn_mfma_f32_16x16x32_bf16(
                            a[mf][ks], b[ks], acc[mf], 0, 0, 0);
#pragma unroll
                for (int mf = 0; mf < 2; ++mf)
#pragma unroll
                    for (int rg = 0; rg < 4; ++rg) {
                        float v = fmaf(-2.0f, acc[mf][rg], sj);
                        float vs = valid ? v : INFINITY;
                        s2[mf][rg] = fminf(s2[mf][rg], fmaxf(s1[mf][rg], vs));
                        s1[mf][rg] = fminf(s1[mf][rg], vs);
                    }
            }
#pragma unroll
            for (int m = 1; m < 16; m <<= 1) {
#pragma unroll
                for (int mf = 0; mf < 2; ++mf)
#pragma unroll
                    for (int rg = 0; rg < 4; ++rg) {
                        float o1 = __shfl_xor(s1[mf][rg], m, 16);
                        float o2 = __shfl_xor(s2[mf][rg], m, 16);
                        float lo = fminf(s1[mf][rg], o1);
                        float hi = fminf(fmaxf(s1[mf][rg], o1), fminf(s2[mf][rg], o2));
                        s1[mf][rg] = lo; s2[mf][rg] = hi;
                    }
            }
            if (c == 0) {
#pragma unroll
                for (int mf = 0; mf < 2; ++mf)
#pragma unroll
                    for (int rg = 0; rg < 4; ++rg) {
                        int islot = ip * 32 + mf * 16 + q * 4 + rg;
                        if (islot < n) {
                            int row = midx[islot];
                            pos_d2[row] = sq[row] + s2[mf][rg];
                        }
                    }
            }
        }
        return;
    }

    // ------- main path: diff-class min, wave tile 64x64, 8 j-tiles --------
    const int mbid = bid - 256;
    const int i0 = (mbid & 31) * 256 + wv * 64;
    const int g = mbid >> 5;  // 0..15
    const int jb = g * 512;

    short8 a[4][4];
#pragma unroll
    for (int mf = 0; mf < 4; ++mf) {
        int row = i0 + mf * 16 + c;
#pragma unroll
        for (int ks = 0; ks < 4; ++ks)
            a[mf][ks] = fbT[(size_t)(ks * 4 + q) * BN + row];
    }
    int li[4][4];
#pragma unroll
    for (int mf = 0; mf < 4; ++mf)
#pragma unroll
        for (int rg = 0; rg < 4; ++rg)
            li[mf][rg] = lbl[i0 + mf * 16 + q * 4 + rg];

    float n1[4][4];
#pragma unroll
    for (int mf = 0; mf < 4; ++mf)
#pragma unroll
        for (int rg = 0; rg < 4; ++rg) n1[mf][rg] = INFINITY;

#pragma unroll 2
    for (int jt = 0; jt < 8; ++jt) {
        const int j0 = jb + jt * 64;

        short8 b[4][4];
#pragma unroll
        for (int ks = 0; ks < 4; ++ks)
#pragma unroll
            for (int nf = 0; nf < 4; ++nf)
                b[ks][nf] = fbT[(size_t)(ks * 4 + q) * BN + j0 + nf * 16 + c];

        int ljv[4]; float sjv[4];
#pragma unroll
        for (int nf = 0; nf < 4; ++nf) {
            int jc = j0 + nf * 16 + c;
            ljv[nf] = lbl[jc];
            sjv[nf] = sq[jc];
        }

        floatx4 acc[4][4];
#pragma unroll
        for (int mf = 0; mf < 4; ++mf)
#pragma unroll
            for (int nf = 0; nf < 4; ++nf) acc[mf][nf] = (floatx4)0.f;

#pragma unroll
        for (int ks = 0; ks < 4; ++ks)
#pragma unroll
            for (int mf = 0; mf < 4; ++mf)
#pragma unroll
                for (int nf = 0; nf < 4; ++nf)
                    acc[mf][nf] = __builtin_amdgcn_mfma_f32_16x16x32_bf16(
                        a[mf][ks], b[ks][nf], acc[mf][nf], 0, 0, 0);

        // neg-only epilogue: 4 ops/element
#pragma unroll
        for (int nf = 0; nf < 4; ++nf) {
#pragma unroll
            for (int mf = 0; mf < 4; ++mf)
#pragma unroll
                for (int rg = 0; rg < 4; ++rg) {
                    float v = fmaf(-2.0f, acc[mf][nf][rg], sjv[nf]);
                    float vd = (li[mf][rg] == ljv[nf]) ? INFINITY : v;
                    n1[mf][rg] = fminf(n1[mf][rg], vd);
                }
        }
    }

    // min across the 16 c-lanes sharing each accumulator row
#pragma unroll
    for (int m = 1; m < 16; m <<= 1) {
#pragma unroll
        for (int mf = 0; mf < 4; ++mf)
#pragma unroll
            for (int rg = 0; rg < 4; ++rg)
                n1[mf][rg] = fminf(n1[mf][rg], __shfl_xor(n1[mf][rg], m, 16));
    }
    if (c == 0) {
#pragma unroll
        for (int mf = 0; mf < 4; ++mf)
#pragma unroll
            for (int rg = 0; rg < 4; ++rg)
                part[g * BN + i0 + mf * 16 + q * 4 + rg] = n1[mf][rg];
    }
}

// combine 16 n1 slices + pos_d2 -> hinge; atomic sum; last block writes mean
__global__ __launch_bounds__(128) void merge_kernel(const float* __restrict__ part,
                                                    const float* __restrict__ sq,
                                                    const float* __restrict__ pos_d2,
                                                    float* __restrict__ g_acc,
                                                    unsigned* __restrict__ counter,
                                                    float* __restrict__ out) {
    int r = blockIdx.x * 128 + threadIdx.x;
    float n = INFINITY;
#pragma unroll
    for (int k = 0; k < 16; ++k) n = fminf(n, part[k * BN + r]);
    float si = sq[r];
    float pos = sqrtf(fmaxf(pos_d2[r] + EPS_F, 0.f));
    float neg = sqrtf(fmaxf(si + n + EPS_F, 0.f));
    float h = fmaxf(MARGIN_F + pos - neg, 0.f);
    __shared__ float red[2];
#pragma unroll
    for (int m = 32; m >= 1; m >>= 1) h += __shfl_down(h, m, 64);
    if ((threadIdx.x & 63) == 0) red[threadIdx.x >> 6] = h;
    __syncthreads();
    if (threadIdx.x == 0) {
        atomicAdd(g_acc, red[0] + red[1]);
        __threadfence();
        unsigned old = atomicAdd(counter, 1u);
        if (old == 63u) {
            float tot = atomicAdd(g_acc, 0.0f);
            out[0] = tot / (float)BN;
        }
    }
}

extern "C" void kernel_launch(void* const* d_in, const int* in_sizes, int n_in,
                              void* d_out, int out_size, void* d_ws, size_t ws_size,
                              hipStream_t stream) {
    const float* f = (const float*)d_in[0];
    const int* lbl = (const int*)d_in[1];
    char* ws = (char*)d_ws;
    float* sq = (float*)ws;                                    // 32 KB
    short8* fbT = (short8*)(ws + 32768);                       // 2 MB
    float* part = (float*)(ws + 32768 + 2097152);              // 512 KB (16 slices)
    float* pos_d2 = (float*)(ws + 32768 + 2097152 + 524288);   // 32 KB
    float* g_acc = (float*)(ws + 32768 + 2097152 + 524288 + 32768);
    unsigned* counter = (unsigned*)(g_acc + 1);
    float* out = (float*)d_out;

    prep_kernel<<<128, 256, 0, stream>>>(f, fbT, sq, g_acc, counter);
    work_kernel<<<768, 256, 0, stream>>>(fbT, lbl, sq, part, pos_d2);
    merge_kernel<<<64, 128, 0, stream>>>(part, sq, pos_d2, g_acc, counter, out);
}

// Round 9
// 100.336 us; speedup vs baseline: 1.5754x; 1.1934x over previous
//
#include <hip/hip_runtime.h>
#include <math.h>

// TripletHard B=8192 D=128 NC=256. Round-9: r8 with (a) main blocks FIRST in
// the grid (pos blocks backfill the tail instead of stealing gen-1 residency),
// (b) per-ks b-loads (peak regs ~200, kills the 33 MB scratch spill),
// (c) pos parallelized across all 4 waves (16-row groups).
//   prep : fp32->bf16 (RNE), K-major fbT, sq of rounded values.
//   work : 768 blocks. [0,512): neg-only diff-class min, wave tile 64x64,
//          A-frags resident, barrier-free. [512,768): per-class Gram ->
//          2nd-smallest same-class d2 (pos_d2).
//   merge: combine 16 n1 slices + pos_d2 -> mean hinge (device atomics).
// fbT8[kc*8192 + row] = features[row][kc*8..kc*8+7], kc=0..15.

#define BN 8192
#define MARGIN_F 1.0f
#define EPS_F 1e-5f

typedef __attribute__((ext_vector_type(8))) short short8;
typedef __attribute__((ext_vector_type(4))) float floatx4;

__device__ __forceinline__ unsigned short bf16_rne(float x, float& r) {
    unsigned u = __float_as_uint(x);
    u += 0x7FFF + ((u >> 16) & 1);
    unsigned short h = (unsigned short)(u >> 16);
    r = __uint_as_float(((unsigned)h) << 16);
    return h;
}

// 4 threads/row: bf16 convert, K-major write, sq from ROUNDED values.
__global__ __launch_bounds__(256) void prep_kernel(const float* __restrict__ f,
                                                   short8* __restrict__ fbT,
                                                   float* __restrict__ sq,
                                                   float* __restrict__ g_acc,
                                                   unsigned* __restrict__ counter) {
    int gid = blockIdx.x * 256 + threadIdx.x;  // 0..32767
    if (gid == 0) { *g_acc = 0.f; *counter = 0u; }
    int row = gid >> 2, part = gid & 3;
    const float4* f4 = (const float4*)f + (size_t)row * 32 + part * 8;
    float s = 0.f;
#pragma unroll
    for (int cc = 0; cc < 4; ++cc) {  // chunk kc = part*4 + cc
        float4 v0 = f4[cc * 2], v1 = f4[cc * 2 + 1];
        float r0, r1, r2, r3, r4, r5, r6, r7;
        short8 o;
        o[0] = (short)bf16_rne(v0.x, r0);
        o[1] = (short)bf16_rne(v0.y, r1);
        o[2] = (short)bf16_rne(v0.z, r2);
        o[3] = (short)bf16_rne(v0.w, r3);
        o[4] = (short)bf16_rne(v1.x, r4);
        o[5] = (short)bf16_rne(v1.y, r5);
        o[6] = (short)bf16_rne(v1.z, r6);
        o[7] = (short)bf16_rne(v1.w, r7);
        fbT[(size_t)(part * 4 + cc) * BN + row] = o;
        s += r0 * r0 + r1 * r1 + r2 * r2 + r3 * r3 +
             r4 * r4 + r5 * r5 + r6 * r6 + r7 * r7;
    }
    s += __shfl_xor(s, 1, 4);
    s += __shfl_xor(s, 2, 4);
    if (part == 0) sq[row] = s;
}

// Fused work kernel. Blocks [0,512): main (full residency in gen 1).
// Blocks [512,768): pos, class = bid-512, backfilled into the main tail.
__global__ __launch_bounds__(256, 2) void work_kernel(const short8* __restrict__ fbT,
                                                      const int* __restrict__ lbl,
                                                      const float* __restrict__ sq,
                                                      float* __restrict__ part,
                                                      float* __restrict__ pos_d2) {
    const int t = threadIdx.x;
    const int lane = t & 63;
    const int wv = t >> 6;
    const int q = lane >> 4, c = lane & 15;
    const int bid = blockIdx.x;

    if (bid >= 512) {
        // ---------------- pos path: per-class 2nd-smallest same-class d2 ---
        __shared__ int midx[256];
        __shared__ int cnt;
        const int cls = bid - 512;
        if (t == 0) cnt = 0;
        __syncthreads();
        for (int r = t; r < BN; r += 256) {
            if (lbl[r] == cls) {
                int p = atomicAdd(&cnt, 1);
                if (p < 256) midx[p] = r;
            }
        }
        __syncthreads();
        int n = cnt < 256 ? cnt : 256;
        if (n == 0) return;
        if (t < 256 && t >= n) midx[t] = midx[0];  // pad
        __syncthreads();

        const int ng = (n + 15) >> 4;  // 16-row groups; wave wv takes ig = wv, wv+4, ...
        for (int ig = wv; ig < ng; ig += 4) {
            short8 a[4];
            int arow = midx[ig * 16 + c];
#pragma unroll
            for (int ks = 0; ks < 4; ++ks)
                a[ks] = fbT[(size_t)(ks * 4 + q) * BN + arow];
            float s1[4], s2[4];
#pragma unroll
            for (int rg = 0; rg < 4; ++rg) { s1[rg] = INFINITY; s2[rg] = INFINITY; }

            for (int s = 0; s < ng; ++s) {  // 16 j-slots per step
                int jslot = s * 16 + c;
                int jrow = midx[jslot];
                short8 b[4];
#pragma unroll
                for (int ks = 0; ks < 4; ++ks)
                    b[ks] = fbT[(size_t)(ks * 4 + q) * BN + jrow];
                float sj = sq[jrow];
                bool valid = (jslot < n);

                floatx4 acc = (floatx4)0.f;
#pragma unroll
                for (int ks = 0; ks < 4; ++ks)
                    acc = __builtin_amdgcn_mfma_f32_16x16x32_bf16(a[ks], b[ks], acc, 0, 0, 0);
#pragma unroll
                for (int rg = 0; rg < 4; ++rg) {
                    float v = fmaf(-2.0f, acc[rg], sj);
                    float vs = valid ? v : INFINITY;
                    s2[rg] = fminf(s2[rg], fmaxf(s1[rg], vs));
                    s1[rg] = fminf(s1[rg], vs);
                }
            }
#pragma unroll
            for (int m = 1; m < 16; m <<= 1) {
#pragma unroll
                for (int rg = 0; rg < 4; ++rg) {
                    float o1 = __shfl_xor(s1[rg], m, 16);
                    float o2 = __shfl_xor(s2[rg], m, 16);
                    float lo = fminf(s1[rg], o1);
                    float hi = fminf(fmaxf(s1[rg], o1), fminf(s2[rg], o2));
                    s1[rg] = lo; s2[rg] = hi;
                }
            }
            if (c == 0) {
#pragma unroll
                for (int rg = 0; rg < 4; ++rg) {
                    int islot = ig * 16 + q * 4 + rg;
                    if (islot < n) {
                        int row = midx[islot];
                        pos_d2[row] = sq[row] + s2[rg];
                    }
                }
            }
        }
        return;
    }

    // ------- main path: diff-class min, wave tile 64x64, 8 j-tiles --------
    const int i0 = (bid & 31) * 256 + wv * 64;
    const int g = bid >> 5;  // 0..15
    const int jb = g * 512;

    short8 a[4][4];
#pragma unroll
    for (int mf = 0; mf < 4; ++mf) {
        int row = i0 + mf * 16 + c;
#pragma unroll
        for (int ks = 0; ks < 4; ++ks)
            a[mf][ks] = fbT[(size_t)(ks * 4 + q) * BN + row];
    }
    int li[4][4];
#pragma unroll
    for (int mf = 0; mf < 4; ++mf)
#pragma unroll
        for (int rg = 0; rg < 4; ++rg)
            li[mf][rg] = lbl[i0 + mf * 16 + q * 4 + rg];

    float n1[4][4];
#pragma unroll
    for (int mf = 0; mf < 4; ++mf)
#pragma unroll
        for (int rg = 0; rg < 4; ++rg) n1[mf][rg] = INFINITY;

#pragma unroll 2
    for (int jt = 0; jt < 8; ++jt) {
        const int j0 = jb + jt * 64;

        int ljv[4]; float sjv[4];
#pragma unroll
        for (int nf = 0; nf < 4; ++nf) {
            int jc = j0 + nf * 16 + c;
            ljv[nf] = lbl[jc];
            sjv[nf] = sq[jc];
        }

        floatx4 acc[4][4];
#pragma unroll
        for (int mf = 0; mf < 4; ++mf)
#pragma unroll
            for (int nf = 0; nf < 4; ++nf) acc[mf][nf] = (floatx4)0.f;

        // per-ks b-loads: peak live b regs ~2 ks worth, no spill (r8 fix)
#pragma unroll
        for (int ks = 0; ks < 4; ++ks) {
            short8 b[4];
#pragma unroll
            for (int nf = 0; nf < 4; ++nf)
                b[nf] = fbT[(size_t)(ks * 4 + q) * BN + j0 + nf * 16 + c];
#pragma unroll
            for (int mf = 0; mf < 4; ++mf)
#pragma unroll
                for (int nf = 0; nf < 4; ++nf)
                    acc[mf][nf] = __builtin_amdgcn_mfma_f32_16x16x32_bf16(
                        a[mf][ks], b[nf], acc[mf][nf], 0, 0, 0);
        }

        // neg-only epilogue: 4 ops/element
#pragma unroll
        for (int nf = 0; nf < 4; ++nf) {
#pragma unroll
            for (int mf = 0; mf < 4; ++mf)
#pragma unroll
                for (int rg = 0; rg < 4; ++rg) {
                    float v = fmaf(-2.0f, acc[mf][nf][rg], sjv[nf]);
                    float vd = (li[mf][rg] == ljv[nf]) ? INFINITY : v;
                    n1[mf][rg] = fminf(n1[mf][rg], vd);
                }
        }
    }

    // min across the 16 c-lanes sharing each accumulator row
#pragma unroll
    for (int m = 1; m < 16; m <<= 1) {
#pragma unroll
        for (int mf = 0; mf < 4; ++mf)
#pragma unroll
            for (int rg = 0; rg < 4; ++rg)
                n1[mf][rg] = fminf(n1[mf][rg], __shfl_xor(n1[mf][rg], m, 16));
    }
    if (c == 0) {
#pragma unroll
        for (int mf = 0; mf < 4; ++mf)
#pragma unroll
            for (int rg = 0; rg < 4; ++rg)
                part[g * BN + i0 + mf * 16 + q * 4 + rg] = n1[mf][rg];
    }
}

// combine 16 n1 slices + pos_d2 -> hinge; atomic sum; last block writes mean
__global__ __launch_bounds__(128) void merge_kernel(const float* __restrict__ part,
                                                    const float* __restrict__ sq,
                                                    const float* __restrict__ pos_d2,
                                                    float* __restrict__ g_acc,
                                                    unsigned* __restrict__ counter,
                                                    float* __restrict__ out) {
    int r = blockIdx.x * 128 + threadIdx.x;
    float n = INFINITY;
#pragma unroll
    for (int k = 0; k < 16; ++k) n = fminf(n, part[k * BN + r]);
    float si = sq[r];
    float pos = sqrtf(fmaxf(pos_d2[r] + EPS_F, 0.f));
    float neg = sqrtf(fmaxf(si + n + EPS_F, 0.f));
    float h = fmaxf(MARGIN_F + pos - neg, 0.f);
    __shared__ float red[2];
#pragma unroll
    for (int m = 32; m >= 1; m >>= 1) h += __shfl_down(h, m, 64);
    if ((threadIdx.x & 63) == 0) red[threadIdx.x >> 6] = h;
    __syncthreads();
    if (threadIdx.x == 0) {
        atomicAdd(g_acc, red[0] + red[1]);
        __threadfence();
        unsigned old = atomicAdd(counter, 1u);
        if (old == 63u) {
            float tot = atomicAdd(g_acc, 0.0f);
            out[0] = tot / (float)BN;
        }
    }
}

extern "C" void kernel_launch(void* const* d_in, const int* in_sizes, int n_in,
                              void* d_out, int out_size, void* d_ws, size_t ws_size,
                              hipStream_t stream) {
    const float* f = (const float*)d_in[0];
    const int* lbl = (const int*)d_in[1];
    char* ws = (char*)d_ws;
    float* sq = (float*)ws;                                    // 32 KB
    short8* fbT = (short8*)(ws + 32768);                       // 2 MB
    float* part = (float*)(ws + 32768 + 2097152);              // 512 KB (16 slices)
    float* pos_d2 = (float*)(ws + 32768 + 2097152 + 524288);   // 32 KB
    float* g_acc = (float*)(ws + 32768 + 2097152 + 524288 + 32768);
    unsigned* counter = (unsigned*)(g_acc + 1);
    float* out = (float*)d_out;

    prep_kernel<<<128, 256, 0, stream>>>(f, fbT, sq, g_acc, counter);
    work_kernel<<<768, 256, 0, stream>>>(fbT, lbl, sq, part, pos_d2);
    merge_kernel<<<64, 128, 0, stream>>>(part, sq, pos_d2, g_acc, counter, out);
}

// Round 10
// 87.965 us; speedup vs baseline: 1.7969x; 1.1406x over previous
//
#include <hip/hip_runtime.h>
#include <math.h>

// TripletHard B=8192 D=128 NC=256. Round-10: 32x64 wave tile (mf=2) so the
// irreducible live set (~140 VGPR) fits lb(256,3)'s 170 cap -> 3 waves/SIMD,
// zero spill (r7/r8/r9 all lost to scratch traffic from the 64x64 tile's
// 128-reg a+acc baseline).
//   prep : fp32->bf16 (RNE), K-major fbT, sq of rounded values.
//   work : 768 blocks = 256 CU x 3. [0,512): neg-only diff-class min, wave
//          tile 32x64, A-frags resident, barrier-free, 16 j-tiles each.
//          [512,768): per-class Gram -> 2nd-smallest same-class d2 (pos_d2).
//   merge: combine 8 n1 slices + pos_d2 -> mean hinge (device atomics).
// fbT8[kc*8192 + row] = features[row][kc*8..kc*8+7], kc=0..15.

#define BN 8192
#define MARGIN_F 1.0f
#define EPS_F 1e-5f

typedef __attribute__((ext_vector_type(8))) short short8;
typedef __attribute__((ext_vector_type(4))) float floatx4;

__device__ __forceinline__ unsigned short bf16_rne(float x, float& r) {
    unsigned u = __float_as_uint(x);
    u += 0x7FFF + ((u >> 16) & 1);
    unsigned short h = (unsigned short)(u >> 16);
    r = __uint_as_float(((unsigned)h) << 16);
    return h;
}

// 4 threads/row: bf16 convert, K-major write, sq from ROUNDED values.
__global__ __launch_bounds__(256) void prep_kernel(const float* __restrict__ f,
                                                   short8* __restrict__ fbT,
                                                   float* __restrict__ sq,
                                                   float* __restrict__ g_acc,
                                                   unsigned* __restrict__ counter) {
    int gid = blockIdx.x * 256 + threadIdx.x;  // 0..32767
    if (gid == 0) { *g_acc = 0.f; *counter = 0u; }
    int row = gid >> 2, part = gid & 3;
    const float4* f4 = (const float4*)f + (size_t)row * 32 + part * 8;
    float s = 0.f;
#pragma unroll
    for (int cc = 0; cc < 4; ++cc) {  // chunk kc = part*4 + cc
        float4 v0 = f4[cc * 2], v1 = f4[cc * 2 + 1];
        float r0, r1, r2, r3, r4, r5, r6, r7;
        short8 o;
        o[0] = (short)bf16_rne(v0.x, r0);
        o[1] = (short)bf16_rne(v0.y, r1);
        o[2] = (short)bf16_rne(v0.z, r2);
        o[3] = (short)bf16_rne(v0.w, r3);
        o[4] = (short)bf16_rne(v1.x, r4);
        o[5] = (short)bf16_rne(v1.y, r5);
        o[6] = (short)bf16_rne(v1.z, r6);
        o[7] = (short)bf16_rne(v1.w, r7);
        fbT[(size_t)(part * 4 + cc) * BN + row] = o;
        s += r0 * r0 + r1 * r1 + r2 * r2 + r3 * r3 +
             r4 * r4 + r5 * r5 + r6 * r6 + r7 * r7;
    }
    s += __shfl_xor(s, 1, 4);
    s += __shfl_xor(s, 2, 4);
    if (part == 0) sq[row] = s;
}

// Fused work kernel. Blocks [0,512): main (resident gen-1, 2 of the 3 slots).
// Blocks [512,768): pos, class = bid-512, fills the 3rd slot.
__global__ __launch_bounds__(256, 3) void work_kernel(const short8* __restrict__ fbT,
                                                      const int* __restrict__ lbl,
                                                      const float* __restrict__ sq,
                                                      float* __restrict__ part,
                                                      float* __restrict__ pos_d2) {
    const int t = threadIdx.x;
    const int lane = t & 63;
    const int wv = t >> 6;
    const int q = lane >> 4, c = lane & 15;
    const int bid = blockIdx.x;

    if (bid >= 512) {
        // ---------------- pos path: per-class 2nd-smallest same-class d2 ---
        __shared__ int midx[256];
        __shared__ int cnt;
        const int cls = bid - 512;
        if (t == 0) cnt = 0;
        __syncthreads();
        for (int r = t; r < BN; r += 256) {
            if (lbl[r] == cls) {
                int p = atomicAdd(&cnt, 1);
                if (p < 256) midx[p] = r;
            }
        }
        __syncthreads();
        int n = cnt < 256 ? cnt : 256;
        if (n == 0) return;
        if (t < 256 && t >= n) midx[t] = midx[0];  // pad
        __syncthreads();

        const int ng = (n + 15) >> 4;  // 16-row groups; wave wv takes ig = wv, wv+4, ...
        for (int ig = wv; ig < ng; ig += 4) {
            short8 a[4];
            int arow = midx[ig * 16 + c];
#pragma unroll
            for (int ks = 0; ks < 4; ++ks)
                a[ks] = fbT[(size_t)(ks * 4 + q) * BN + arow];
            float s1[4], s2[4];
#pragma unroll
            for (int rg = 0; rg < 4; ++rg) { s1[rg] = INFINITY; s2[rg] = INFINITY; }

            for (int s = 0; s < ng; ++s) {  // 16 j-slots per step
                int jslot = s * 16 + c;
                int jrow = midx[jslot];
                short8 b[4];
#pragma unroll
                for (int ks = 0; ks < 4; ++ks)
                    b[ks] = fbT[(size_t)(ks * 4 + q) * BN + jrow];
                float sj = sq[jrow];
                bool valid = (jslot < n);

                floatx4 acc = (floatx4)0.f;
#pragma unroll
                for (int ks = 0; ks < 4; ++ks)
                    acc = __builtin_amdgcn_mfma_f32_16x16x32_bf16(a[ks], b[ks], acc, 0, 0, 0);
#pragma unroll
                for (int rg = 0; rg < 4; ++rg) {
                    float v = fmaf(-2.0f, acc[rg], sj);
                    float vs = valid ? v : INFINITY;
                    s2[rg] = fminf(s2[rg], fmaxf(s1[rg], vs));
                    s1[rg] = fminf(s1[rg], vs);
                }
            }
#pragma unroll
            for (int m = 1; m < 16; m <<= 1) {
#pragma unroll
                for (int rg = 0; rg < 4; ++rg) {
                    float o1 = __shfl_xor(s1[rg], m, 16);
                    float o2 = __shfl_xor(s2[rg], m, 16);
                    float lo = fminf(s1[rg], o1);
                    float hi = fminf(fmaxf(s1[rg], o1), fminf(s2[rg], o2));
                    s1[rg] = lo; s2[rg] = hi;
                }
            }
            if (c == 0) {
#pragma unroll
                for (int rg = 0; rg < 4; ++rg) {
                    int islot = ig * 16 + q * 4 + rg;
                    if (islot < n) {
                        int row = midx[islot];
                        pos_d2[row] = sq[row] + s2[rg];
                    }
                }
            }
        }
        return;
    }

    // ------- main path: diff-class min, wave tile 32x64, 16 j-tiles -------
    const int i0 = (bid & 63) * 128 + wv * 32;  // 64 i-blocks x 4 waves x 32 rows
    const int g = bid >> 6;  // 0..7
    const int jb = g * 1024;

    short8 a[2][4];
#pragma unroll
    for (int mf = 0; mf < 2; ++mf) {
        int row = i0 + mf * 16 + c;
#pragma unroll
        for (int ks = 0; ks < 4; ++ks)
            a[mf][ks] = fbT[(size_t)(ks * 4 + q) * BN + row];
    }
    int li[2][4];
#pragma unroll
    for (int mf = 0; mf < 2; ++mf)
#pragma unroll
        for (int rg = 0; rg < 4; ++rg)
            li[mf][rg] = lbl[i0 + mf * 16 + q * 4 + rg];

    float n1[2][4];
#pragma unroll
    for (int mf = 0; mf < 2; ++mf)
#pragma unroll
        for (int rg = 0; rg < 4; ++rg) n1[mf][rg] = INFINITY;

#pragma unroll 2
    for (int jt = 0; jt < 16; ++jt) {
        const int j0 = jb + jt * 64;

        int ljv[4]; float sjv[4];
#pragma unroll
        for (int nf = 0; nf < 4; ++nf) {
            int jc = j0 + nf * 16 + c;
            ljv[nf] = lbl[jc];
            sjv[nf] = sq[jc];
        }

        floatx4 acc[2][4];
#pragma unroll
        for (int mf = 0; mf < 2; ++mf)
#pragma unroll
            for (int nf = 0; nf < 4; ++nf) acc[mf][nf] = (floatx4)0.f;

#pragma unroll
        for (int ks = 0; ks < 4; ++ks) {
            short8 b[4];
#pragma unroll
            for (int nf = 0; nf < 4; ++nf)
                b[nf] = fbT[(size_t)(ks * 4 + q) * BN + j0 + nf * 16 + c];
#pragma unroll
            for (int mf = 0; mf < 2; ++mf)
#pragma unroll
                for (int nf = 0; nf < 4; ++nf)
                    acc[mf][nf] = __builtin_amdgcn_mfma_f32_16x16x32_bf16(
                        a[mf][ks], b[nf], acc[mf][nf], 0, 0, 0);
        }

        // neg-only epilogue: 4 ops/element
#pragma unroll
        for (int nf = 0; nf < 4; ++nf) {
#pragma unroll
            for (int mf = 0; mf < 2; ++mf)
#pragma unroll
                for (int rg = 0; rg < 4; ++rg) {
                    float v = fmaf(-2.0f, acc[mf][nf][rg], sjv[nf]);
                    float vd = (li[mf][rg] == ljv[nf]) ? INFINITY : v;
                    n1[mf][rg] = fminf(n1[mf][rg], vd);
                }
        }
    }

    // min across the 16 c-lanes sharing each accumulator row
#pragma unroll
    for (int m = 1; m < 16; m <<= 1) {
#pragma unroll
        for (int mf = 0; mf < 2; ++mf)
#pragma unroll
            for (int rg = 0; rg < 4; ++rg)
                n1[mf][rg] = fminf(n1[mf][rg], __shfl_xor(n1[mf][rg], m, 16));
    }
    if (c == 0) {
#pragma unroll
        for (int mf = 0; mf < 2; ++mf)
#pragma unroll
            for (int rg = 0; rg < 4; ++rg)
                part[g * BN + i0 + mf * 16 + q * 4 + rg] = n1[mf][rg];
    }
}

// combine 8 n1 slices + pos_d2 -> hinge; atomic sum; last block writes mean
__global__ __launch_bounds__(128) void merge_kernel(const float* __restrict__ part,
                                                    const float* __restrict__ sq,
                                                    const float* __restrict__ pos_d2,
                                                    float* __restrict__ g_acc,
                                                    unsigned* __restrict__ counter,
                                                    float* __restrict__ out) {
    int r = blockIdx.x * 128 + threadIdx.x;
    float n = INFINITY;
#pragma unroll
    for (int k = 0; k < 8; ++k) n = fminf(n, part[k * BN + r]);
    float si = sq[r];
    float pos = sqrtf(fmaxf(pos_d2[r] + EPS_F, 0.f));
    float neg = sqrtf(fmaxf(si + n + EPS_F, 0.f));
    float h = fmaxf(MARGIN_F + pos - neg, 0.f);
    __shared__ float red[2];
#pragma unroll
    for (int m = 32; m >= 1; m >>= 1) h += __shfl_down(h, m, 64);
    if ((threadIdx.x & 63) == 0) red[threadIdx.x >> 6] = h;
    __syncthreads();
    if (threadIdx.x == 0) {
        atomicAdd(g_acc, red[0] + red[1]);
        __threadfence();
        unsigned old = atomicAdd(counter, 1u);
        if (old == 63u) {
            float tot = atomicAdd(g_acc, 0.0f);
            out[0] = tot / (float)BN;
        }
    }
}

extern "C" void kernel_launch(void* const* d_in, const int* in_sizes, int n_in,
                              void* d_out, int out_size, void* d_ws, size_t ws_size,
                              hipStream_t stream) {
    const float* f = (const float*)d_in[0];
    const int* lbl = (const int*)d_in[1];
    char* ws = (char*)d_ws;
    float* sq = (float*)ws;                                    // 32 KB
    short8* fbT = (short8*)(ws + 32768);                       // 2 MB
    float* part = (float*)(ws + 32768 + 2097152);              // 256 KB (8 slices)
    float* pos_d2 = (float*)(ws + 32768 + 2097152 + 262144);   // 32 KB
    float* g_acc = (float*)(ws + 32768 + 2097152 + 262144 + 32768);
    unsigned* counter = (unsigned*)(g_acc + 1);
    float* out = (float*)d_out;

    prep_kernel<<<128, 256, 0, stream>>>(f, fbT, sq, g_acc, counter);
    work_kernel<<<768, 256, 0, stream>>>(fbT, lbl, sq, part, pos_d2);
    merge_kernel<<<64, 128, 0, stream>>>(part, sq, pos_d2, g_acc, counter, out);
}